// Round 7
// baseline (299.075 us; speedup 1.0000x reference)
//
#include <hip/hip_runtime.h>

#define EPS 1e-5f

typedef float f32x4 __attribute__((ext_vector_type(4)));
typedef short short8_t __attribute__((ext_vector_type(8)));
typedef unsigned int uint4v __attribute__((ext_vector_type(4)));
typedef unsigned short ushort_t;

// ---------------- prep: fold BN(+bias), build bf16 weight fragments ----------------
// prm (floats): [0..31] s1, [32..63] sh1, [64..127] s2, [128..191] sh2,
//               [192..703] s3, [704..1215] sh3
// w1frag (ushort): [plane=2][nt=2][lane=64][j=8]; oc=nt*16+(l&15), tap=(l>>4)*8+j (0 if tap>=25)
// w2frag (ushort): [kk=25][nt=4][lane=64][j=8]; oc=nt*16+(l&15), ic=(l>>4)*8+j
// w3frag (ushort): [ks=32][ntg=32][lane=64][j=8]; oc=ntg*16+(l&15), k=ks*32+(l>>4)*8+j
__global__ void prep_kernel(const float* __restrict__ b1, const float* __restrict__ g1,
                            const float* __restrict__ be1, const float* __restrict__ m1,
                            const float* __restrict__ v1,
                            const float* __restrict__ b2, const float* __restrict__ g2,
                            const float* __restrict__ be2, const float* __restrict__ m2,
                            const float* __restrict__ v2,
                            const float* __restrict__ b3, const float* __restrict__ g3,
                            const float* __restrict__ be3, const float* __restrict__ m3,
                            const float* __restrict__ v3,
                            const float* __restrict__ w1, const float* __restrict__ w2,
                            const float* __restrict__ w3,
                            ushort_t* __restrict__ w1frag, ushort_t* __restrict__ w2frag,
                            ushort_t* __restrict__ w3frag, float* __restrict__ prm) {
  int tid = blockIdx.x * blockDim.x + threadIdx.x;
  int stride = gridDim.x * blockDim.x;
  for (int c = tid; c < 32; c += stride) {
    float s = g1[c] / sqrtf(v1[c] + EPS);
    prm[c] = s;
    prm[32 + c] = (b1[c] - m1[c]) * s + be1[c];
  }
  for (int c = tid; c < 64; c += stride) {
    float s = g2[c] / sqrtf(v2[c] + EPS);
    prm[64 + c] = s;
    prm[128 + c] = (b2[c] - m2[c]) * s + be2[c];
  }
  for (int c = tid; c < 512; c += stride) {
    float s = g3[c] / sqrtf(v3[c] + EPS);
    prm[192 + c] = s;
    prm[704 + c] = (b3[c] - m3[c]) * s + be3[c];
  }
  // w1frag: hi/lo planes (w1 is NOT ternary)
  for (int i = tid; i < 2 * 2 * 64 * 8; i += stride) {
    const int j = i & 7;
    const int l = (i >> 3) & 63;
    const int nt = (i >> 9) & 1;
    const int p = i >> 10;
    const int oc = nt * 16 + (l & 15);
    const int t = (l >> 4) * 8 + j;
    const float v = (t < 25) ? w1[oc * 25 + t] : 0.f;
    const unsigned u = __float_as_uint(v);
    const ushort_t hi = (ushort_t)(u >> 16);
    const float r = v - __uint_as_float(u & 0xffff0000u);
    const ushort_t lo = (ushort_t)(__float_as_uint(r) >> 16);
    w1frag[i] = p ? lo : hi;
  }
  // w2: [64][32][5][5]; ternary -> bf16 truncation exact
  for (int i = tid; i < 25 * 4 * 64 * 8; i += stride) {
    const int kk = i >> 11;
    const int r = i & 2047;
    const int nt = r >> 9;
    const int r2 = r & 511;
    const int l = r2 >> 3;
    const int j = r2 & 7;
    const int oc = nt * 16 + (l & 15);
    const int ic = (l >> 4) * 8 + j;
    w2frag[i] = (ushort_t)(__float_as_uint(w2[oc * 800 + ic * 25 + kk]) >> 16);
  }
  // w3: [512][1024] ternary
  for (int i = tid; i < 32 * 32 * 64 * 8; i += stride) {
    const int ks = i >> 14;
    const int r = i & 16383;
    const int ntg = r >> 9;
    const int r2 = r & 511;
    const int l = r2 >> 3;
    const int j = r2 & 7;
    const int oc = ntg * 16 + (l & 15);
    const int k = ks * 32 + (l >> 4) * 8 + j;
    w3frag[i] = (ushort_t)(__float_as_uint(w3[oc * 1024 + k]) >> 16);
  }
}

// ---------------- fused conv1+bn1+relu+pool1 + conv2+bn2+relu+pool2, all MFMA ----------------
// Block = 256 threads = 4 waves sharing ONE image (26.2 KB LDS). launch_bounds(256,5)
// -> VGPR<=102 -> 5 blocks/CU = 20 waves/CU.
// conv1: wave w does m-tiles w*9..w*9+8 (all 32 ocs). conv2: wave w owns pixel-tile
// mt2=w (pooled row Y2=w) x ALL 4 oc-tiles; per-tap weight loads from L2 (4 waves read
// identical addresses ~in phase -> L1 reuse). Per-image conv2 A-reads stay at 200 b128.
// Image stored in LDS pre-packed bf16 (hi<<16|lo) -> conv1 repack is 8 bit-ops.
// insA cell stride 80 B keeps ds_read_b128 conflict-free/2-way.
// q-ordering (q = cell*4 + sub) makes each C-fragment's 4 regs = one 2x2 pool window.
__launch_bounds__(256, 5)
__global__ void conv12_kernel(const float* __restrict__ x,
                              const ushort_t* __restrict__ w1frag,
                              const ushort_t* __restrict__ w2frag,
                              const float* __restrict__ prm,
                              ushort_t* __restrict__ h2pH, ushort_t* __restrict__ h2pL) {
  __shared__ __align__(16) unsigned char lds[26240];

  const int tid = threadIdx.x;
  const int w = tid >> 6, l = tid & 63;
  const int b = blockIdx.x;
  const int m15 = l & 15, g = l >> 4;

  unsigned* imgP = (unsigned*)lds;                  // 800 u32: (bf16hi<<16)|bf16lo
  ushort_t* insA = (ushort_t*)(lds + 3200);         // 2 planes x 144 cells x 40 ushorts

  // --- stage the image into LDS, packed hi|lo ---
  const float* xb = x + (size_t)b * 784;
  for (int i = tid; i < 784; i += 256) {
    const float v = xb[i];
    const unsigned u = __float_as_uint(v);
    const float r = v - __uint_as_float(u & 0xffff0000u);
    imgP[i] = (u & 0xffff0000u) | (__float_as_uint(r) >> 16);
  }
  if (tid < 16) imgP[784 + tid] = 0u;

  // --- conv1 B-frags (hi/lo), 16 VGPRs ---
  short8_t B1h[2], B1l[2];
#pragma unroll
  for (int nt = 0; nt < 2; ++nt) {
    B1h[nt] = *(const short8_t*)(w1frag + (size_t)(nt * 64 + l) * 8);
    B1l[nt] = *(const short8_t*)(w1frag + (size_t)((2 + nt) * 64 + l) * 8);
  }

  // per-lane tap offsets for this lane's k-group (fake taps clamped; B=0 there)
  int off[8];
#pragma unroll
  for (int j = 0; j < 8; ++j) {
    const int t = g * 8 + j;
    const int ky = t / 5, kx = t - ky * 5;
    off[j] = (t < 25) ? (ky * 28 + kx) : 0;
  }

  // BN params in regs
  float s1[2], sh1[2], s2[4], sh2[4];
#pragma unroll
  for (int nt = 0; nt < 2; ++nt) {
    s1[nt] = prm[nt * 16 + m15];
    sh1[nt] = prm[32 + nt * 16 + m15];
  }
#pragma unroll
  for (int nt = 0; nt < 4; ++nt) {
    s2[nt] = prm[64 + nt * 16 + m15];
    sh2[nt] = prm[128 + nt * 16 + m15];
  }
  __syncthreads();

  // ---- conv1: 9 m-tiles per wave; 6 MFMAs each (AhBh+AlBh+AhBl x 2 nt) ----
#pragma unroll 3
  for (int i = 0; i < 9; ++i) {
    const int mt = w * 9 + i;
    const int q = mt * 16 + m15;
    const int p_pool = q >> 2, sub = q & 3;
    const int py = p_pool / 12, px = p_pool - py * 12;
    const int Y = 2 * py + (sub >> 1), X = 2 * px + (sub & 1);
    const unsigned* pixb = imgP + Y * 28 + X;
    unsigned pv[8];
#pragma unroll
    for (int j = 0; j < 8; ++j) pv[j] = pixb[off[j]];
    uint4v hv, lv;
#pragma unroll
    for (int k = 0; k < 4; ++k) {
      hv[k] = (pv[2 * k] >> 16) | (pv[2 * k + 1] & 0xffff0000u);
      lv[k] = (pv[2 * k] & 0xffffu) | (pv[2 * k + 1] << 16);
    }
    const short8_t ah = __builtin_bit_cast(short8_t, hv);
    const short8_t al = __builtin_bit_cast(short8_t, lv);

    f32x4 c0 = {0.f, 0.f, 0.f, 0.f}, c1 = {0.f, 0.f, 0.f, 0.f};
    c0 = __builtin_amdgcn_mfma_f32_16x16x32_bf16(ah, B1h[0], c0, 0, 0, 0);
    c1 = __builtin_amdgcn_mfma_f32_16x16x32_bf16(ah, B1h[1], c1, 0, 0, 0);
    c0 = __builtin_amdgcn_mfma_f32_16x16x32_bf16(al, B1h[0], c0, 0, 0, 0);
    c1 = __builtin_amdgcn_mfma_f32_16x16x32_bf16(al, B1h[1], c1, 0, 0, 0);
    c0 = __builtin_amdgcn_mfma_f32_16x16x32_bf16(ah, B1l[0], c0, 0, 0, 0);
    c1 = __builtin_amdgcn_mfma_f32_16x16x32_bf16(ah, B1l[1], c1, 0, 0, 0);

    // epilogue: 4 regs = 2x2 pool window (q-order); bn+relu; hi/lo -> insA
    const int cell = mt * 4 + g;
#pragma unroll
    for (int nt = 0; nt < 2; ++nt) {
      const f32x4 c = nt ? c1 : c0;
      const float pvv = fmaxf(fmaxf(c[0], c[1]), fmaxf(c[2], c[3]));
      const float a = fmaxf(fmaf(pvv, s1[nt], sh1[nt]), 0.f);
      const unsigned u = __float_as_uint(a);
      const float r = a - __uint_as_float(u & 0xffff0000u);
      const int ic = nt * 16 + m15;
      insA[cell * 40 + ic] = (ushort_t)(u >> 16);
      insA[5760 + cell * 40 + ic] = (ushort_t)(__float_as_uint(r) >> 16);
    }
  }
  __syncthreads();

  // ---- conv2: wave owns pixel-tile mt2=w x all 4 oc-tiles; per-ky A-preload ----
  const int sy = (m15 & 3) >> 1, sx = m15 & 1;
  const int X2 = 2 * (m15 >> 2) + sx;

  f32x4 acc[4];
#pragma unroll
  for (int nt = 0; nt < 4; ++nt) acc[nt] = (f32x4){0.f, 0.f, 0.f, 0.f};

#pragma unroll 1
  for (int ky = 0; ky < 5; ++ky) {
    const int rowb = (2 * w + sy + ky) * 12 + X2;
    short8_t a[5][2];
#pragma unroll
    for (int kx = 0; kx < 5; ++kx) {
      a[kx][0] = *(const short8_t*)(insA + (rowb + kx) * 40 + g * 8);
      a[kx][1] = *(const short8_t*)(insA + 5760 + (rowb + kx) * 40 + g * 8);
    }
#pragma unroll
    for (int kx = 0; kx < 5; ++kx) {
      const ushort_t* wp = w2frag + (size_t)(((ky * 5 + kx) * 4) * 64 + l) * 8;
      const short8_t b0 = *(const short8_t*)(wp);
      const short8_t b1 = *(const short8_t*)(wp + 512);
      const short8_t b2 = *(const short8_t*)(wp + 1024);
      const short8_t b3 = *(const short8_t*)(wp + 1536);
      acc[0] = __builtin_amdgcn_mfma_f32_16x16x32_bf16(a[kx][0], b0, acc[0], 0, 0, 0);
      acc[0] = __builtin_amdgcn_mfma_f32_16x16x32_bf16(a[kx][1], b0, acc[0], 0, 0, 0);
      acc[1] = __builtin_amdgcn_mfma_f32_16x16x32_bf16(a[kx][0], b1, acc[1], 0, 0, 0);
      acc[1] = __builtin_amdgcn_mfma_f32_16x16x32_bf16(a[kx][1], b1, acc[1], 0, 0, 0);
      acc[2] = __builtin_amdgcn_mfma_f32_16x16x32_bf16(a[kx][0], b2, acc[2], 0, 0, 0);
      acc[2] = __builtin_amdgcn_mfma_f32_16x16x32_bf16(a[kx][1], b2, acc[2], 0, 0, 0);
      acc[3] = __builtin_amdgcn_mfma_f32_16x16x32_bf16(a[kx][0], b3, acc[3], 0, 0, 0);
      acc[3] = __builtin_amdgcn_mfma_f32_16x16x32_bf16(a[kx][1], b3, acc[3], 0, 0, 0);
    }
  }

  // ---- conv2 epilogue: in-lane 2x2 pool, bn2+relu, hi/lo -> h2p ----
  const size_t ob = (size_t)b * 1024;
  const int cell2 = w * 4 + g;
#pragma unroll
  for (int nt = 0; nt < 4; ++nt) {
    const f32x4 c = acc[nt];
    const float pvv = fmaxf(fmaxf(c[0], c[1]), fmaxf(c[2], c[3]));
    const float a = fmaxf(fmaf(pvv, s2[nt], sh2[nt]), 0.f);
    const unsigned u = __float_as_uint(a);
    const float r = a - __uint_as_float(u & 0xffff0000u);
    const int oc = nt * 16 + m15;
    h2pH[ob + oc * 16 + cell2] = (ushort_t)(u >> 16);
    h2pL[ob + oc * 16 + cell2] = (ushort_t)(__float_as_uint(r) >> 16);
  }
}

// ---------------- fc3 (1024->512) + bn3 + relu via bf16 MFMA, no LDS ----------------
// grid (8,128); XCD-chunked swizzle; merged hi/lo accumulator (C accumulates both)
__launch_bounds__(256)
__global__ void fc3_kernel(const ushort_t* __restrict__ h2pH, const ushort_t* __restrict__ h2pL,
                           const ushort_t* __restrict__ w3frag, const float* __restrict__ prm,
                           float* __restrict__ a3) {
  const int orig = blockIdx.x + (blockIdx.y << 3);
  const int xcd = orig & 7;
  const int j = orig >> 3;
  const int ytile = (xcd << 4) | (j >> 3);
  const int xtile = j & 7;
  const int n0 = xtile * 64;
  const int m0 = ytile * 64;
  const int w = threadIdx.x >> 6, l = threadIdx.x & 63;
  const int mrow = m0 + w * 16 + (l & 15);
  const int kc8 = (l >> 4) * 8;

  const ushort_t* aHp = h2pH + (size_t)mrow * 1024 + kc8;
  const ushort_t* aLp = h2pL + (size_t)mrow * 1024 + kc8;
  const ushort_t* bp = w3frag + (size_t)(n0 >> 4) * 512 + (size_t)l * 8;

  f32x4 acc[4];
#pragma unroll
  for (int t = 0; t < 4; ++t) acc[t] = (f32x4){0.f, 0.f, 0.f, 0.f};

#pragma unroll 4
  for (int ks = 0; ks < 32; ++ks) {
    const short8_t aH = *(const short8_t*)(aHp + ks * 32);
    const short8_t aL = *(const short8_t*)(aLp + ks * 32);
    const ushort_t* bks = bp + (size_t)ks * 16384;
#pragma unroll
    for (int t = 0; t < 4; ++t) {
      const short8_t bb = *(const short8_t*)(bks + t * 512);
      acc[t] = __builtin_amdgcn_mfma_f32_16x16x32_bf16(aH, bb, acc[t], 0, 0, 0);
      acc[t] = __builtin_amdgcn_mfma_f32_16x16x32_bf16(aL, bb, acc[t], 0, 0, 0);
    }
  }

#pragma unroll
  for (int t = 0; t < 4; ++t) {
    const int oc = n0 + t * 16 + (l & 15);
    const float s = prm[192 + oc], sh = prm[704 + oc];
#pragma unroll
    for (int r = 0; r < 4; ++r) {
      const int m = m0 + w * 16 + (l >> 4) * 4 + r;
      a3[(size_t)m * 512 + oc] = fmaxf(fmaf(acc[t][r], s, sh), 0.f);
    }
  }
}

// ---------------- fc4 (512->10), one wave per batch row ----------------
__launch_bounds__(256)
__global__ void fc4_kernel(const float* __restrict__ a3, const float* __restrict__ w4,
                           float* __restrict__ out, int B) {
  const int w = threadIdx.x >> 6, l = threadIdx.x & 63;
  const int b = blockIdx.x * 4 + w;
  if (b >= B) return;
  const float4* ar = (const float4*)(a3 + (size_t)b * 512);
  const float4 a0 = ar[l * 2];
  const float4 a1 = ar[l * 2 + 1];
#pragma unroll
  for (int j = 0; j < 10; ++j) {
    const float4* wr = (const float4*)(w4 + j * 512);
    const float4 w0 = wr[l * 2];
    const float4 w1 = wr[l * 2 + 1];
    float sv = a0.x * w0.x + a0.y * w0.y + a0.z * w0.z + a0.w * w0.w +
               a1.x * w1.x + a1.y * w1.y + a1.z * w1.z + a1.w * w1.w;
#pragma unroll
    for (int off = 1; off < 64; off <<= 1) sv += __shfl_xor(sv, off);
    if (l == 0) out[(size_t)b * 10 + j] = sv;
  }
}

extern "C" void kernel_launch(void* const* d_in, const int* in_sizes, int n_in,
                              void* d_out, int out_size, void* d_ws, size_t ws_size,
                              hipStream_t stream) {
  const float* x  = (const float*)d_in[0];
  const float* w1 = (const float*)d_in[1];
  const float* b1 = (const float*)d_in[2];
  const float* g1 = (const float*)d_in[3];
  const float* be1 = (const float*)d_in[4];
  const float* m1 = (const float*)d_in[5];
  const float* v1 = (const float*)d_in[6];
  const float* w2 = (const float*)d_in[7];
  const float* b2 = (const float*)d_in[8];
  const float* g2 = (const float*)d_in[9];
  const float* be2 = (const float*)d_in[10];
  const float* m2 = (const float*)d_in[11];
  const float* v2 = (const float*)d_in[12];
  const float* w3 = (const float*)d_in[13];
  const float* b3 = (const float*)d_in[14];
  const float* g3 = (const float*)d_in[15];
  const float* be3 = (const float*)d_in[16];
  const float* m3 = (const float*)d_in[17];
  const float* v3 = (const float*)d_in[18];
  const float* w4 = (const float*)d_in[19];

  const int B = in_sizes[0] / 784;  // 8192

  float* prm = (float*)d_ws;                          // 1216 f32
  ushort_t* w1frag = (ushort_t*)(prm + 1216);         // 2048
  ushort_t* w2frag = w1frag + 2048;                   // 51200
  ushort_t* w3frag = w2frag + 51200;                  // 524288
  ushort_t* h2pH = w3frag + 524288;                   // B*1024
  ushort_t* h2pL = h2pH + (size_t)B * 1024;           // B*1024
  float* a3 = (float*)(h2pL + (size_t)B * 1024);      // B*512 f32

  prep_kernel<<<64, 256, 0, stream>>>(b1, g1, be1, m1, v1, b2, g2, be2, m2, v2,
                                      b3, g3, be3, m3, v3, w1, w2, w3,
                                      w1frag, w2frag, w3frag, prm);
  conv12_kernel<<<B, 256, 0, stream>>>(x, w1frag, w2frag, prm, h2pH, h2pL);
  dim3 g3d(8, B / 64);
  fc3_kernel<<<g3d, 256, 0, stream>>>(h2pH, h2pL, w3frag, prm, a3);
  fc4_kernel<<<(B + 3) / 4, 256, 0, stream>>>(a3, w4, (float*)d_out, B);
}

// Round 8
// 262.687 us; speedup vs baseline: 1.1385x; 1.1385x over previous
//
#include <hip/hip_runtime.h>

#define EPS 1e-5f

typedef float f32x4 __attribute__((ext_vector_type(4)));
typedef short short8_t __attribute__((ext_vector_type(8)));
typedef unsigned int uint4v __attribute__((ext_vector_type(4)));
typedef unsigned short ushort_t;

// ---------------- prep: fold BN(+bias), build bf16 weight fragments ----------------
// prm (floats): [0..31] s1, [32..63] sh1, [64..127] s2, [128..191] sh2,
//               [192..703] s3, [704..1215] sh3
// w1frag (ushort): [plane=2][nt=2][lane=64][j=8]; oc=nt*16+(l&15), tap=(l>>4)*8+j (0 if tap>=25)
// w2frag (ushort): [kk=25][nt=4][lane=64][j=8]; oc=nt*16+(l&15), ic=(l>>4)*8+j
// w3frag (ushort): [ks=32][ntg=32][lane=64][j=8]; oc=ntg*16+(l&15), k=ks*32+(l>>4)*8+j
__global__ void prep_kernel(const float* __restrict__ b1, const float* __restrict__ g1,
                            const float* __restrict__ be1, const float* __restrict__ m1,
                            const float* __restrict__ v1,
                            const float* __restrict__ b2, const float* __restrict__ g2,
                            const float* __restrict__ be2, const float* __restrict__ m2,
                            const float* __restrict__ v2,
                            const float* __restrict__ b3, const float* __restrict__ g3,
                            const float* __restrict__ be3, const float* __restrict__ m3,
                            const float* __restrict__ v3,
                            const float* __restrict__ w1, const float* __restrict__ w2,
                            const float* __restrict__ w3,
                            ushort_t* __restrict__ w1frag, ushort_t* __restrict__ w2frag,
                            ushort_t* __restrict__ w3frag, float* __restrict__ prm) {
  int tid = blockIdx.x * blockDim.x + threadIdx.x;
  int stride = gridDim.x * blockDim.x;
  for (int c = tid; c < 32; c += stride) {
    float s = g1[c] / sqrtf(v1[c] + EPS);
    prm[c] = s;
    prm[32 + c] = (b1[c] - m1[c]) * s + be1[c];
  }
  for (int c = tid; c < 64; c += stride) {
    float s = g2[c] / sqrtf(v2[c] + EPS);
    prm[64 + c] = s;
    prm[128 + c] = (b2[c] - m2[c]) * s + be2[c];
  }
  for (int c = tid; c < 512; c += stride) {
    float s = g3[c] / sqrtf(v3[c] + EPS);
    prm[192 + c] = s;
    prm[704 + c] = (b3[c] - m3[c]) * s + be3[c];
  }
  // w1frag: hi/lo planes (w1 is NOT ternary)
  for (int i = tid; i < 2 * 2 * 64 * 8; i += stride) {
    const int j = i & 7;
    const int l = (i >> 3) & 63;
    const int nt = (i >> 9) & 1;
    const int p = i >> 10;
    const int oc = nt * 16 + (l & 15);
    const int t = (l >> 4) * 8 + j;
    const float v = (t < 25) ? w1[oc * 25 + t] : 0.f;
    const unsigned u = __float_as_uint(v);
    const ushort_t hi = (ushort_t)(u >> 16);
    const float r = v - __uint_as_float(u & 0xffff0000u);
    const ushort_t lo = (ushort_t)(__float_as_uint(r) >> 16);
    w1frag[i] = p ? lo : hi;
  }
  // w2: [64][32][5][5]; ternary -> bf16 truncation exact
  for (int i = tid; i < 25 * 4 * 64 * 8; i += stride) {
    const int kk = i >> 11;
    const int r = i & 2047;
    const int nt = r >> 9;
    const int r2 = r & 511;
    const int l = r2 >> 3;
    const int j = r2 & 7;
    const int oc = nt * 16 + (l & 15);
    const int ic = (l >> 4) * 8 + j;
    w2frag[i] = (ushort_t)(__float_as_uint(w2[oc * 800 + ic * 25 + kk]) >> 16);
  }
  // w3: [512][1024] ternary
  for (int i = tid; i < 32 * 32 * 64 * 8; i += stride) {
    const int ks = i >> 14;
    const int r = i & 16383;
    const int ntg = r >> 9;
    const int r2 = r & 511;
    const int l = r2 >> 3;
    const int j = r2 & 7;
    const int oc = ntg * 16 + (l & 15);
    const int k = ks * 32 + (l >> 4) * 8 + j;
    w3frag[i] = (ushort_t)(__float_as_uint(w3[oc * 1024 + k]) >> 16);
  }
}

// ---------------- fused conv1+bn1+relu+pool1 + conv2+bn2+relu+pool2, all MFMA ----------------
// Round-6 structure (validated 144 us): block = 128 threads = 2 waves sharing ONE image
// (26.2 KB -> 6 blocks/CU, 12 waves/CU). conv1: wave w does m-tiles w*18..w*18+17.
// conv2: wave w does pixel-tiles {2w,2w+1} x all 4 oc-tiles, weights register-resident
// in 5 ky-passes. Image stored packed (bf16hi<<16)|bf16lo -> gather unpack = bit-ops.
// insA cell stride 80 B keeps ds_read_b128 conflict-free/2-way.
// q-ordering (q = cell*4 + sub) makes each C-fragment's 4 regs = one 2x2 pool window.
__launch_bounds__(128)
__global__ void conv12_kernel(const float* __restrict__ x,
                              const ushort_t* __restrict__ w1frag,
                              const ushort_t* __restrict__ w2frag,
                              const float* __restrict__ prm,
                              ushort_t* __restrict__ h2pH, ushort_t* __restrict__ h2pL) {
  __shared__ __align__(16) unsigned char lds[26240];

  const int tid = threadIdx.x;
  const int w = tid >> 6, l = tid & 63;
  const int b = blockIdx.x;
  const int m15 = l & 15, g = l >> 4;

  unsigned* imgP = (unsigned*)lds;                  // 800 u32: (bf16hi<<16)|bf16lo
  ushort_t* insA = (ushort_t*)(lds + 3200);         // 2 planes x 144 cells x 40 ushorts

  // --- stage the image into LDS, packed hi|lo ---
  const float* xb = x + (size_t)b * 784;
  for (int i = tid; i < 784; i += 128) {
    const float v = xb[i];
    const unsigned u = __float_as_uint(v);
    const float r = v - __uint_as_float(u & 0xffff0000u);
    imgP[i] = (u & 0xffff0000u) | (__float_as_uint(r) >> 16);
  }
  if (tid < 16) imgP[784 + tid] = 0u;

  // --- conv1 B-frags (hi/lo), 16 VGPRs ---
  short8_t B1h[2], B1l[2];
#pragma unroll
  for (int nt = 0; nt < 2; ++nt) {
    B1h[nt] = *(const short8_t*)(w1frag + (size_t)(nt * 64 + l) * 8);
    B1l[nt] = *(const short8_t*)(w1frag + (size_t)((2 + nt) * 64 + l) * 8);
  }

  // per-lane tap offsets for this lane's k-group (fake taps clamped; B=0 there)
  int off[8];
#pragma unroll
  for (int j = 0; j < 8; ++j) {
    const int t = g * 8 + j;
    const int ky = t / 5, kx = t - ky * 5;
    off[j] = (t < 25) ? (ky * 28 + kx) : 0;
  }

  // BN params in regs
  float s1[2], sh1[2], s2[4], sh2[4];
#pragma unroll
  for (int nt = 0; nt < 2; ++nt) {
    s1[nt] = prm[nt * 16 + m15];
    sh1[nt] = prm[32 + nt * 16 + m15];
  }
#pragma unroll
  for (int nt = 0; nt < 4; ++nt) {
    s2[nt] = prm[64 + nt * 16 + m15];
    sh2[nt] = prm[128 + nt * 16 + m15];
  }
  __syncthreads();

  // ---- conv1: 18 m-tiles per wave; 6 MFMAs each (AhBh+AlBh+AhBl x 2 nt) ----
#pragma unroll 1
  for (int i = 0; i < 18; ++i) {
    const int mt = w * 18 + i;
    const int q = mt * 16 + m15;
    const int p_pool = q >> 2, sub = q & 3;
    const int py = p_pool / 12, px = p_pool - py * 12;
    const int Y = 2 * py + (sub >> 1), X = 2 * px + (sub & 1);
    const unsigned* pixb = imgP + Y * 28 + X;
    unsigned pv[8];
#pragma unroll
    for (int j = 0; j < 8; ++j) pv[j] = pixb[off[j]];
    uint4v hv, lv;
#pragma unroll
    for (int k = 0; k < 4; ++k) {
      hv[k] = (pv[2 * k] >> 16) | (pv[2 * k + 1] & 0xffff0000u);
      lv[k] = (pv[2 * k] & 0xffffu) | (pv[2 * k + 1] << 16);
    }
    const short8_t ah = __builtin_bit_cast(short8_t, hv);
    const short8_t al = __builtin_bit_cast(short8_t, lv);

    f32x4 c0 = {0.f, 0.f, 0.f, 0.f}, c1 = {0.f, 0.f, 0.f, 0.f};
    c0 = __builtin_amdgcn_mfma_f32_16x16x32_bf16(ah, B1h[0], c0, 0, 0, 0);
    c1 = __builtin_amdgcn_mfma_f32_16x16x32_bf16(ah, B1h[1], c1, 0, 0, 0);
    c0 = __builtin_amdgcn_mfma_f32_16x16x32_bf16(al, B1h[0], c0, 0, 0, 0);
    c1 = __builtin_amdgcn_mfma_f32_16x16x32_bf16(al, B1h[1], c1, 0, 0, 0);
    c0 = __builtin_amdgcn_mfma_f32_16x16x32_bf16(ah, B1l[0], c0, 0, 0, 0);
    c1 = __builtin_amdgcn_mfma_f32_16x16x32_bf16(ah, B1l[1], c1, 0, 0, 0);

    // epilogue: 4 regs = 2x2 pool window (q-order); bn+relu; hi/lo -> insA
    const int cell = mt * 4 + g;
#pragma unroll
    for (int nt = 0; nt < 2; ++nt) {
      const f32x4 c = nt ? c1 : c0;
      const float pvv = fmaxf(fmaxf(c[0], c[1]), fmaxf(c[2], c[3]));
      const float a = fmaxf(fmaf(pvv, s1[nt], sh1[nt]), 0.f);
      const unsigned u = __float_as_uint(a);
      const float r = a - __uint_as_float(u & 0xffff0000u);
      const int ic = nt * 16 + m15;
      insA[cell * 40 + ic] = (ushort_t)(u >> 16);
      insA[5760 + cell * 40 + ic] = (ushort_t)(__float_as_uint(r) >> 16);
    }
  }
  __syncthreads();

  // ---- conv2: wave owns pixel-tiles {2w, 2w+1} x all 4 oc-tiles; 5 ky-passes ----
  const int sy = (m15 & 3) >> 1, sx = m15 & 1;
  const int X2 = 2 * (m15 >> 2) + sx;

  f32x4 acc[2][4];
#pragma unroll
  for (int m = 0; m < 2; ++m)
#pragma unroll
    for (int nt = 0; nt < 4; ++nt) acc[m][nt] = (f32x4){0.f, 0.f, 0.f, 0.f};

#pragma unroll 1
  for (int pass = 0; pass < 5; ++pass) {
    short8_t wr[5][4];
#pragma unroll
    for (int kx = 0; kx < 5; ++kx)
#pragma unroll
      for (int nt = 0; nt < 4; ++nt)
        wr[kx][nt] = *(const short8_t*)(w2frag + (size_t)(((pass * 5 + kx) * 4 + nt) * 64 + l) * 8);
#pragma unroll
    for (int kx = 0; kx < 5; ++kx) {
#pragma unroll
      for (int m = 0; m < 2; ++m) {
        const int mt2 = 2 * w + m;
        const int cellin = (2 * mt2 + sy + pass) * 12 + X2 + kx;
        const short8_t aH = *(const short8_t*)(insA + cellin * 40 + g * 8);
        const short8_t aL = *(const short8_t*)(insA + 5760 + cellin * 40 + g * 8);
#pragma unroll
        for (int nt = 0; nt < 4; ++nt) {
          acc[m][nt] = __builtin_amdgcn_mfma_f32_16x16x32_bf16(aH, wr[kx][nt], acc[m][nt], 0, 0, 0);
          acc[m][nt] = __builtin_amdgcn_mfma_f32_16x16x32_bf16(aL, wr[kx][nt], acc[m][nt], 0, 0, 0);
        }
      }
    }
  }

  // ---- conv2 epilogue: in-lane 2x2 pool, bn2+relu, hi/lo -> h2p ----
  const size_t ob = (size_t)b * 1024;
#pragma unroll
  for (int m = 0; m < 2; ++m) {
    const int cell2 = (2 * w + m) * 4 + g;
#pragma unroll
    for (int nt = 0; nt < 4; ++nt) {
      const f32x4 c = acc[m][nt];
      const float pvv = fmaxf(fmaxf(c[0], c[1]), fmaxf(c[2], c[3]));
      const float a = fmaxf(fmaf(pvv, s2[nt], sh2[nt]), 0.f);
      const unsigned u = __float_as_uint(a);
      const float r = a - __uint_as_float(u & 0xffff0000u);
      const int oc = nt * 16 + m15;
      h2pH[ob + oc * 16 + cell2] = (ushort_t)(u >> 16);
      h2pL[ob + oc * 16 + cell2] = (ushort_t)(__float_as_uint(r) >> 16);
    }
  }
}

// ---------------- fc3 (1024->512) + bn3 + relu via bf16 MFMA, no LDS ----------------
// Tile 64 rows x 128 ocs, grid (4,128) = 512 blocks (2/CU, 8 waves/CU).
// Wave = 16 rows x 128 ocs: per ks-step 16 MFMA : 10 b128 loads; acc = 32 VGPR.
// XCD swizzle: the 4 n-blocks sharing an A-panel -> same XCD L2.
__launch_bounds__(256)
__global__ void fc3_kernel(const ushort_t* __restrict__ h2pH, const ushort_t* __restrict__ h2pL,
                           const ushort_t* __restrict__ w3frag, const float* __restrict__ prm,
                           float* __restrict__ a3) {
  const int orig = blockIdx.x + (blockIdx.y << 2);
  const int xcd = orig & 7;
  const int j = orig >> 3;              // 0..63
  const int ytile = (xcd << 4) | (j >> 2);   // 0..127
  const int xtile = j & 3;              // 0..3
  const int n0 = xtile * 128;
  const int m0 = ytile * 64;
  const int w = threadIdx.x >> 6, l = threadIdx.x & 63;
  const int mrow = m0 + w * 16 + (l & 15);
  const int kc8 = (l >> 4) * 8;

  const ushort_t* aHp = h2pH + (size_t)mrow * 1024 + kc8;
  const ushort_t* aLp = h2pL + (size_t)mrow * 1024 + kc8;
  const ushort_t* bp = w3frag + (size_t)(n0 >> 4) * 512 + (size_t)l * 8;

  f32x4 acc[8];
#pragma unroll
  for (int t = 0; t < 8; ++t) acc[t] = (f32x4){0.f, 0.f, 0.f, 0.f};

#pragma unroll 2
  for (int ks = 0; ks < 32; ++ks) {
    const short8_t aH = *(const short8_t*)(aHp + ks * 32);
    const short8_t aL = *(const short8_t*)(aLp + ks * 32);
    const ushort_t* bks = bp + (size_t)ks * 16384;
#pragma unroll
    for (int t = 0; t < 8; ++t) {
      const short8_t bb = *(const short8_t*)(bks + t * 512);
      acc[t] = __builtin_amdgcn_mfma_f32_16x16x32_bf16(aH, bb, acc[t], 0, 0, 0);
      acc[t] = __builtin_amdgcn_mfma_f32_16x16x32_bf16(aL, bb, acc[t], 0, 0, 0);
    }
  }

#pragma unroll
  for (int t = 0; t < 8; ++t) {
    const int oc = n0 + t * 16 + (l & 15);
    const float s = prm[192 + oc], sh = prm[704 + oc];
#pragma unroll
    for (int r = 0; r < 4; ++r) {
      const int m = m0 + w * 16 + (l >> 4) * 4 + r;
      a3[(size_t)m * 512 + oc] = fmaxf(fmaf(acc[t][r], s, sh), 0.f);
    }
  }
}

// ---------------- fc4 (512->10), one wave per batch row ----------------
__launch_bounds__(256)
__global__ void fc4_kernel(const float* __restrict__ a3, const float* __restrict__ w4,
                           float* __restrict__ out, int B) {
  const int w = threadIdx.x >> 6, l = threadIdx.x & 63;
  const int b = blockIdx.x * 4 + w;
  if (b >= B) return;
  const float4* ar = (const float4*)(a3 + (size_t)b * 512);
  const float4 a0 = ar[l * 2];
  const float4 a1 = ar[l * 2 + 1];
#pragma unroll
  for (int j = 0; j < 10; ++j) {
    const float4* wr = (const float4*)(w4 + j * 512);
    const float4 w0 = wr[l * 2];
    const float4 w1 = wr[l * 2 + 1];
    float sv = a0.x * w0.x + a0.y * w0.y + a0.z * w0.z + a0.w * w0.w +
               a1.x * w1.x + a1.y * w1.y + a1.z * w1.z + a1.w * w1.w;
#pragma unroll
    for (int off = 1; off < 64; off <<= 1) sv += __shfl_xor(sv, off);
    if (l == 0) out[(size_t)b * 10 + j] = sv;
  }
}

extern "C" void kernel_launch(void* const* d_in, const int* in_sizes, int n_in,
                              void* d_out, int out_size, void* d_ws, size_t ws_size,
                              hipStream_t stream) {
  const float* x  = (const float*)d_in[0];
  const float* w1 = (const float*)d_in[1];
  const float* b1 = (const float*)d_in[2];
  const float* g1 = (const float*)d_in[3];
  const float* be1 = (const float*)d_in[4];
  const float* m1 = (const float*)d_in[5];
  const float* v1 = (const float*)d_in[6];
  const float* w2 = (const float*)d_in[7];
  const float* b2 = (const float*)d_in[8];
  const float* g2 = (const float*)d_in[9];
  const float* be2 = (const float*)d_in[10];
  const float* m2 = (const float*)d_in[11];
  const float* v2 = (const float*)d_in[12];
  const float* w3 = (const float*)d_in[13];
  const float* b3 = (const float*)d_in[14];
  const float* g3 = (const float*)d_in[15];
  const float* be3 = (const float*)d_in[16];
  const float* m3 = (const float*)d_in[17];
  const float* v3 = (const float*)d_in[18];
  const float* w4 = (const float*)d_in[19];

  const int B = in_sizes[0] / 784;  // 8192

  float* prm = (float*)d_ws;                          // 1216 f32
  ushort_t* w1frag = (ushort_t*)(prm + 1216);         // 2048
  ushort_t* w2frag = w1frag + 2048;                   // 51200
  ushort_t* w3frag = w2frag + 51200;                  // 524288
  ushort_t* h2pH = w3frag + 524288;                   // B*1024
  ushort_t* h2pL = h2pH + (size_t)B * 1024;           // B*1024
  float* a3 = (float*)(h2pL + (size_t)B * 1024);      // B*512 f32

  prep_kernel<<<256, 256, 0, stream>>>(b1, g1, be1, m1, v1, b2, g2, be2, m2, v2,
                                       b3, g3, be3, m3, v3, w1, w2, w3,
                                       w1frag, w2frag, w3frag, prm);
  conv12_kernel<<<B, 128, 0, stream>>>(x, w1frag, w2frag, prm, h2pH, h2pL);
  dim3 g3d(4, B / 64);
  fc3_kernel<<<g3d, 256, 0, stream>>>(h2pH, h2pL, w3frag, prm, a3);
  fc4_kernel<<<(B + 3) / 4, 256, 0, stream>>>(a3, w4, (float*)d_out, B);
}